// Round 1
// baseline (3644.835 us; speedup 1.0000x reference)
//
#include <hip/hip_runtime.h>
#include <math.h>

#define BB 16
#define NN 4096
#define MM 1024
#define CC 64
#define KNN 32
#define R2 0.04f
#define EPSV 1e-5f
#define CIN1 67
#define C1 64
#define C2 128
#define C3 256
#define S1f ((float)(BB * MM * KNN))
#define S3f ((float)(BB * MM))

__device__ __forceinline__ float gelu_f(float x) {
    return 0.5f * x * (1.0f + erff(x * 0.70710678118654752f));
}

// ---------------- ball query ----------------
// grid: B*16 blocks of 64 threads; each thread = one query point.
// Stages the whole src_xyz[b] (48KB) in LDS; serial in-order scan gives
// "first K indices within radius" exactly like the top_k(-score) reference.
__global__ __launch_bounds__(64) void k_ballquery(const float* __restrict__ src_xyz,
                                                  const float* __restrict__ xyz,
                                                  int* __restrict__ gidx) {
    __shared__ float sxyz[NN * 3];
    int b = blockIdx.x >> 4;
    int m = ((blockIdx.x & 15) << 6) + threadIdx.x;
    const float* sp = src_xyz + (size_t)b * NN * 3;
    for (int i = threadIdx.x; i < NN * 3; i += 64) sxyz[i] = sp[i];
    __syncthreads();
    float qx = xyz[((size_t)b * MM + m) * 3 + 0];
    float qy = xyz[((size_t)b * MM + m) * 3 + 1];
    float qz = xyz[((size_t)b * MM + m) * 3 + 2];
    int* out = gidx + ((size_t)b * MM + m) * KNN;
    int cnt = 0;
    int firstj = 0;
    for (int j = 0; j < NN; ++j) {
        float dx = qx - sxyz[j * 3 + 0];
        float dy = qy - sxyz[j * 3 + 1];
        float dz = qz - sxyz[j * 3 + 2];
        float d2 = dx * dx + dy * dy + dz * dz;
        if (d2 <= R2) {
            if (cnt == 0) firstj = j;
            out[cnt] = j;
            ++cnt;
            if (cnt == KNN) break;
        }
    }
    for (int k = cnt; k < KNN; ++k) out[k] = firstj;
}

// ---------------- group loader (shared by stats/layer kernels) ----------------
// feat layout: [KNN][68] (67 used). First __syncthreads doubles as the
// inter-group barrier (previous compute phases must be done before feat is
// overwritten).
__device__ __forceinline__ void load_group(int g, const int* __restrict__ gidx,
                                           const float* __restrict__ src_xyz,
                                           const float* __restrict__ xyz,
                                           const float* __restrict__ src_x,
                                           float* feat, int* sidx) {
    int t = threadIdx.x;
    int b = g >> 10;
    int m = g & (MM - 1);
    if (t < KNN) sidx[t] = gidx[(size_t)g * KNN + t];
    __syncthreads();
    if (t < KNN * 3) {
        int k = t / 3, d = t % 3;
        feat[k * 68 + d] = src_xyz[((size_t)b * NN + sidx[k]) * 3 + d]
                         - xyz[((size_t)b * MM + m) * 3 + d];
    }
    for (int r = t; r < KNN * CC; r += 256) {
        int k = r >> 6, c = r & 63;
        feat[k * 68 + 3 + c] = src_x[((size_t)b * NN + sidx[k]) * CC + c];
    }
    __syncthreads();
}

// ---------------- stats for BN1 ----------------
// stats[0..63]=sum1, [64..127]=sumsq1
__global__ __launch_bounds__(256) void k_stats1(const int* __restrict__ gidx,
                                                const float* __restrict__ src_xyz,
                                                const float* __restrict__ xyz,
                                                const float* __restrict__ src_x,
                                                const float* __restrict__ w1,
                                                float* __restrict__ stats) {
    __shared__ float feat[KNN * 68];
    __shared__ float w1t[CIN1 * C1];
    __shared__ int sidx[KNN];
    __shared__ float red[512];
    int t = threadIdx.x;
    for (int i = t; i < CIN1 * C1; i += 256) {
        int c = i >> 6, o = i & 63;
        w1t[i] = w1[o * CIN1 + c];
    }
    int ch = t & 63, ksub = t >> 6;
    float lsum = 0.f, lsq = 0.f;
    int g0 = blockIdx.x * 8;
    for (int gi = 0; gi < 8; ++gi) {
        load_group(g0 + gi, gidx, src_xyz, xyz, src_x, feat, sidx);
        for (int kk = ksub; kk < KNN; kk += 4) {
            float h = 0.f;
#pragma unroll
            for (int c = 0; c < CIN1; ++c) h += feat[kk * 68 + c] * w1t[c * C1 + ch];
            lsum += h;
            lsq += h * h;
        }
    }
    red[t] = lsum; red[256 + t] = lsq;
    __syncthreads();
    if (t < 64) {
        float s = red[t] + red[t + 64] + red[t + 128] + red[t + 192];
        float q = red[256 + t] + red[256 + t + 64] + red[256 + t + 128] + red[256 + t + 192];
        atomicAdd(&stats[t], s);
        atomicAdd(&stats[64 + t], q);
    }
}

// ---------------- stats for BN2 (recomputes h1) ----------------
// stats[128..255]=sum2, [256..383]=sumsq2
__global__ __launch_bounds__(256) void k_stats2(const int* __restrict__ gidx,
                                                const float* __restrict__ src_xyz,
                                                const float* __restrict__ xyz,
                                                const float* __restrict__ src_x,
                                                const float* __restrict__ w1,
                                                const float* __restrict__ g1,
                                                const float* __restrict__ b1,
                                                const float* __restrict__ w2,
                                                float* __restrict__ stats) {
    __shared__ float feat[KNN * 68];
    __shared__ float w2t[C1 * C2];
    __shared__ float h1s[KNN * C1];
    __shared__ int sidx[KNN];
    __shared__ float sc1[C1], sh1[C1];
    __shared__ float red[512];
    int t = threadIdx.x;
    for (int i = t; i < C1 * C2; i += 256) {
        int c = i >> 7, o = i & 127;
        w2t[i] = w2[o * C1 + c];
    }
    if (t < C1) {
        float mu = stats[t] * (1.f / S1f);
        float var = stats[64 + t] * (1.f / S1f) - mu * mu;
        float rs = rsqrtf(var + EPSV);
        float sc = g1[t] * rs;
        sc1[t] = sc;
        sh1[t] = b1[t] - mu * sc;
    }
    int ch = t & 63, ksub = t >> 6;
    int c2 = t & 127, ks2 = t >> 7;
    float lsum = 0.f, lsq = 0.f;
    int g0 = blockIdx.x * 8;
    for (int gi = 0; gi < 8; ++gi) {
        load_group(g0 + gi, gidx, src_xyz, xyz, src_x, feat, sidx);
        const float* w1r = w1 + ch * CIN1;  // per-lane row, L1-resident (17KB)
        for (int kk = ksub; kk < KNN; kk += 4) {
            float h = 0.f;
#pragma unroll
            for (int c = 0; c < CIN1; ++c) h += feat[kk * 68 + c] * w1r[c];
            h1s[kk * C1 + ch] = gelu_f(h * sc1[ch] + sh1[ch]);
        }
        __syncthreads();
        for (int kk = ks2; kk < KNN; kk += 2) {
            float h = 0.f;
#pragma unroll
            for (int c = 0; c < C1; ++c) h += h1s[kk * C1 + c] * w2t[c * C2 + c2];
            lsum += h;
            lsq += h * h;
        }
    }
    red[t] = lsum; red[256 + t] = lsq;
    __syncthreads();
    if (t < 128) {
        atomicAdd(&stats[128 + t], red[t] + red[t + 128]);
        atomicAdd(&stats[256 + t], red[256 + t] + red[256 + t + 128]);
    }
}

// ---------------- layer3: recompute h1,h2; einsum3 + max over K ----------------
// writes pre-BN output to d_out; stats[384..639]=sum3, [640..895]=sumsq3
__global__ __launch_bounds__(256) void k_layer3(const int* __restrict__ gidx,
                                                const float* __restrict__ src_xyz,
                                                const float* __restrict__ xyz,
                                                const float* __restrict__ src_x,
                                                const float* __restrict__ w1,
                                                const float* __restrict__ g1,
                                                const float* __restrict__ b1,
                                                const float* __restrict__ w2,
                                                const float* __restrict__ g2,
                                                const float* __restrict__ b2,
                                                const float* __restrict__ w3,
                                                float* __restrict__ stats,
                                                float* __restrict__ out) {
    __shared__ float buf[KNN * C2];   // feat (first 32*68) then h2 (32*128)
    __shared__ float w2t[C1 * C2];
    __shared__ float h1s[KNN * C1];
    __shared__ int sidx[KNN];
    __shared__ float sc1[C1], sh1[C1], sc2[C2], sh2[C2];
    int t = threadIdx.x;
    for (int i = t; i < C1 * C2; i += 256) {
        int c = i >> 7, o = i & 127;
        w2t[i] = w2[o * C1 + c];
    }
    if (t < C1) {
        float mu = stats[t] * (1.f / S1f);
        float var = stats[64 + t] * (1.f / S1f) - mu * mu;
        float rs = rsqrtf(var + EPSV);
        float sc = g1[t] * rs;
        sc1[t] = sc;
        sh1[t] = b1[t] - mu * sc;
    }
    if (t < C2) {
        float mu = stats[128 + t] * (1.f / S1f);
        float var = stats[256 + t] * (1.f / S1f) - mu * mu;
        float rs = rsqrtf(var + EPSV);
        float sc = g2[t] * rs;
        sc2[t] = sc;
        sh2[t] = b2[t] - mu * sc;
    }
    int ch = t & 63, ksub = t >> 6;
    int c2 = t & 127, ks2 = t >> 7;
    int o = t;
    float ls3 = 0.f, lq3 = 0.f;
    int g0 = blockIdx.x * 4;
    for (int gi = 0; gi < 4; ++gi) {
        int g = g0 + gi;
        load_group(g, gidx, src_xyz, xyz, src_x, buf, sidx);
        const float* w1r = w1 + ch * CIN1;
        // layer1 -> h1s
        for (int kk = ksub; kk < KNN; kk += 4) {
            float h = 0.f;
#pragma unroll
            for (int c = 0; c < CIN1; ++c) h += buf[kk * 68 + c] * w1r[c];
            h1s[kk * C1 + ch] = gelu_f(h * sc1[ch] + sh1[ch]);
        }
        __syncthreads();
        // layer2 -> h2 (into buf; feat now dead)
        for (int kk = ks2; kk < KNN; kk += 2) {
            float h = 0.f;
#pragma unroll
            for (int c = 0; c < C1; ++c) h += h1s[kk * C1 + c] * w2t[c * C2 + c2];
            buf[kk * C2 + c2] = gelu_f(h * sc2[c2] + sh2[c2]);
        }
        __syncthreads();
        // layer3: each thread owns output channel o; max over K
        float acc[KNN];
#pragma unroll
        for (int k = 0; k < KNN; ++k) acc[k] = 0.f;
        const float* w3r = w3 + o * C2;
        for (int c = 0; c < C2; c += 4) {
            float4 wv = *(const float4*)(w3r + c);
#pragma unroll
            for (int k = 0; k < KNN; ++k) {
                float4 hv = *(const float4*)&buf[k * C2 + c];
                acc[k] += wv.x * hv.x + wv.y * hv.y + wv.z * hv.z + wv.w * hv.w;
            }
        }
        float mx = acc[0];
#pragma unroll
        for (int k = 1; k < KNN; ++k) mx = fmaxf(mx, acc[k]);
        out[(size_t)g * C3 + o] = mx;
        ls3 += mx;
        lq3 += mx * mx;
    }
    atomicAdd(&stats[384 + o], ls3);
    atomicAdd(&stats[640 + o], lq3);
}

// ---------------- final BN + GELU (in-place on d_out) ----------------
__global__ __launch_bounds__(256) void k_bn3(float* __restrict__ out,
                                             const float* __restrict__ stats,
                                             const float* __restrict__ gl,
                                             const float* __restrict__ bl) {
    int i = blockIdx.x * 256 + threadIdx.x;
    if (i >= BB * MM * C3) return;
    int o = i & 255;
    float mu = stats[384 + o] * (1.f / S3f);
    float var = stats[640 + o] * (1.f / S3f) - mu * mu;
    float rs = rsqrtf(var + EPSV);
    float x = out[i];
    out[i] = gelu_f((x - mu) * rs * gl[o] + bl[o]);
}

extern "C" void kernel_launch(void* const* d_in, const int* in_sizes, int n_in,
                              void* d_out, int out_size, void* d_ws, size_t ws_size,
                              hipStream_t stream) {
    const float* src_x   = (const float*)d_in[0];
    const float* src_xyz = (const float*)d_in[1];
    const float* xyz     = (const float*)d_in[2];
    const float* w1      = (const float*)d_in[3];
    const float* g1      = (const float*)d_in[4];
    const float* b1      = (const float*)d_in[5];
    const float* w2      = (const float*)d_in[6];
    const float* g2      = (const float*)d_in[7];
    const float* b2      = (const float*)d_in[8];
    const float* w3      = (const float*)d_in[9];
    const float* gl      = (const float*)d_in[10];
    const float* bl      = (const float*)d_in[11];
    float* out = (float*)d_out;

    int* gidx = (int*)d_ws;
    float* stats = (float*)d_ws + (size_t)BB * MM * KNN;  // 896 floats

    hipMemsetAsync(stats, 0, 896 * sizeof(float), stream);
    k_ballquery<<<BB * 16, 64, 0, stream>>>(src_xyz, xyz, gidx);
    k_stats1<<<(BB * MM) / 8, 256, 0, stream>>>(gidx, src_xyz, xyz, src_x, w1, stats);
    k_stats2<<<(BB * MM) / 8, 256, 0, stream>>>(gidx, src_xyz, xyz, src_x, w1, g1, b1, w2, stats);
    k_layer3<<<(BB * MM) / 4, 256, 0, stream>>>(gidx, src_xyz, xyz, src_x, w1, g1, b1, w2, g2, b2,
                                                w3, stats, out);
    k_bn3<<<(BB * MM * C3) / 256, 256, 0, stream>>>(out, stats, gl, bl);
}

// Round 2
// 785.191 us; speedup vs baseline: 4.6420x; 4.6420x over previous
//
#include <hip/hip_runtime.h>
#include <math.h>

#define BB 16
#define NN 4096
#define MM 1024
#define KNN 32
#define R2 0.04f
#define EPSV 1e-5f
#define S1f ((float)(BB * MM * KNN))
#define S3f ((float)(BB * MM))

typedef __attribute__((ext_vector_type(8))) short short8;
typedef __attribute__((ext_vector_type(4))) float f32x4;

__device__ __forceinline__ short f2b(float x) {
    union { float f; unsigned u; } v; v.f = x;
    unsigned r = v.u + 0x7fffu + ((v.u >> 16) & 1u);
    return (short)(r >> 16);
}
__device__ __forceinline__ float gelu_t(float x) {  // tanh-approx (inner layers, BN-washed)
    float u = 0.7978845608f * x * (1.f + 0.044715f * x * x);
    float t = 1.f - 2.f / (__expf(2.f * u) + 1.f);
    return 0.5f * x * (1.f + t);
}
__device__ __forceinline__ float gelu_e(float x) {  // exact (final output)
    return 0.5f * x * (1.f + erff(x * 0.7071067811865475f));
}
__device__ __forceinline__ f32x4 zero4() { f32x4 z = {0.f, 0.f, 0.f, 0.f}; return z; }
__device__ __forceinline__ f32x4 mfma(short8 a, short8 b, f32x4 c) {
    return __builtin_amdgcn_mfma_f32_16x16x32_bf16(a, b, c, 0, 0, 0);
}

// ---------------- ball query ----------------
__global__ __launch_bounds__(64) void k_ballquery(const float* __restrict__ src_xyz,
                                                  const float* __restrict__ xyz,
                                                  int* __restrict__ gidx) {
    __shared__ float sxyz[NN * 3];
    int b = blockIdx.x >> 4;
    int m = ((blockIdx.x & 15) << 6) + threadIdx.x;
    const float* sp = src_xyz + (size_t)b * NN * 3;
    for (int i = threadIdx.x; i < NN * 3; i += 64) sxyz[i] = sp[i];
    __syncthreads();
    float qx = xyz[((size_t)b * MM + m) * 3 + 0];
    float qy = xyz[((size_t)b * MM + m) * 3 + 1];
    float qz = xyz[((size_t)b * MM + m) * 3 + 2];
    int* out = gidx + ((size_t)b * MM + m) * KNN;
    int cnt = 0, firstj = 0;
    for (int j = 0; j < NN; ++j) {
        float dx = qx - sxyz[j * 3 + 0];
        float dy = qy - sxyz[j * 3 + 1];
        float dz = qz - sxyz[j * 3 + 2];
        float d2 = dx * dx + dy * dy + dz * dz;
        if (d2 <= R2) {
            if (cnt == 0) firstj = j;
            out[cnt] = j;
            ++cnt;
            if (cnt == KNN) break;
        }
    }
    for (int k = cnt; k < KNN; ++k) out[k] = firstj;
}

// ---------------- weights -> bf16 (w1 zero-padded K 67->96) ----------------
__global__ __launch_bounds__(256) void k_prep(const float* __restrict__ w1,
                                              const float* __restrict__ w2,
                                              const float* __restrict__ w3,
                                              short* __restrict__ w1b,
                                              short* __restrict__ w2b,
                                              short* __restrict__ w3b) {
    int i = blockIdx.x * 256 + threadIdx.x;
    if (i < 64 * 96) {
        int n = i / 96, k = i % 96;
        w1b[i] = (k < 67) ? f2b(w1[n * 67 + k]) : (short)0;
    } else if (i < 64 * 96 + 128 * 64) {
        int j = i - 64 * 96;
        w2b[j] = f2b(w2[j]);
    } else if (i < 64 * 96 + 128 * 64 + 256 * 128) {
        int j = i - (64 * 96 + 128 * 64);
        w3b[j] = f2b(w3[j]);
    }
}

// ---------------- gather 128 rows (4 groups) into featS[128][72] bf16 ----------------
__device__ __forceinline__ void gather_feat(int g0, const int* __restrict__ gidx,
                                            const float* __restrict__ src_xyz,
                                            const float* __restrict__ xyz,
                                            const float* __restrict__ src_x,
                                            short* featS, int* sidx) {
    int t = threadIdx.x;
    if (t < 128) sidx[t] = gidx[(size_t)(g0 + (t >> 5)) * KNN + (t & 31)];
    __syncthreads();
    if (t < 128) {
        int gg = g0 + (t >> 5);
        int b = gg >> 10, m = gg & 1023;
        int j = sidx[t];
        const float* sp = src_xyz + ((size_t)b * NN + j) * 3;
        const float* qp = xyz + ((size_t)b * MM + m) * 3;
        short* d = featS + t * 72;
        d[0] = f2b(sp[0] - qp[0]);
        d[1] = f2b(sp[1] - qp[1]);
        d[2] = f2b(sp[2] - qp[2]);
        d[67] = 0; d[68] = 0; d[69] = 0; d[70] = 0; d[71] = 0;
    }
    {
        int r = t >> 1, hf = t & 1;
        int gg = g0 + (r >> 5);
        int b = gg >> 10;
        const f32x4* xp = (const f32x4*)(src_x + ((size_t)b * NN + sidx[r]) * 64 + hf * 32);
        short* d = featS + r * 72 + 3 + hf * 32;
#pragma unroll
        for (int i = 0; i < 8; ++i) {
            f32x4 v = xp[i];
            d[i * 4 + 0] = f2b(v[0]); d[i * 4 + 1] = f2b(v[1]);
            d[i * 4 + 2] = f2b(v[2]); d[i * 4 + 3] = f2b(v[3]);
        }
    }
    __syncthreads();
}

__device__ __forceinline__ void layer1_mfma(const short* featS, const short* __restrict__ w1b,
                                            int lane, int w, f32x4 acc[2][4]) {
#pragma unroll
    for (int rf = 0; rf < 2; ++rf)
#pragma unroll
        for (int nf = 0; nf < 4; ++nf) acc[rf][nf] = zero4();
    short8 bw[3][4];
#pragma unroll
    for (int kf = 0; kf < 3; ++kf)
#pragma unroll
        for (int nf = 0; nf < 4; ++nf)
            bw[kf][nf] = *(const short8*)(w1b + (nf * 16 + (lane & 15)) * 96 + kf * 32 + (lane >> 4) * 8);
#pragma unroll
    for (int rf = 0; rf < 2; ++rf) {
#pragma unroll
        for (int kf = 0; kf < 3; ++kf) {
            short8 a = {0, 0, 0, 0, 0, 0, 0, 0};
            if (kf < 2 || (lane >> 4) == 0)
                a = *(const short8*)(featS + (w * 32 + rf * 16 + (lane & 15)) * 72 + kf * 32 + (lane >> 4) * 8);
#pragma unroll
            for (int nf = 0; nf < 4; ++nf) acc[rf][nf] = mfma(a, bw[kf][nf], acc[rf][nf]);
        }
    }
}

// ---------------- stats1 ----------------
__global__ __launch_bounds__(256, 2) void k_s1(const int* __restrict__ gidx,
                                               const float* __restrict__ src_xyz,
                                               const float* __restrict__ xyz,
                                               const float* __restrict__ src_x,
                                               const short* __restrict__ w1b,
                                               float* __restrict__ stats1) {
    __shared__ short featS[128 * 72];
    __shared__ int sidx[128];
    __shared__ float redS[256], redQ[256];
    int t = threadIdx.x, lane = t & 63, w = t >> 6;
    gather_feat(blockIdx.x * 4, gidx, src_xyz, xyz, src_x, featS, sidx);
    f32x4 acc[2][4];
    layer1_mfma(featS, w1b, lane, w, acc);
#pragma unroll
    for (int nf = 0; nf < 4; ++nf) {
        float s = 0.f, q = 0.f;
#pragma unroll
        for (int rf = 0; rf < 2; ++rf)
#pragma unroll
            for (int j = 0; j < 4; ++j) { float v = acc[rf][nf][j]; s += v; q += v * v; }
        s += __shfl_xor(s, 16); s += __shfl_xor(s, 32);
        q += __shfl_xor(q, 16); q += __shfl_xor(q, 32);
        if (lane < 16) { redS[w * 64 + nf * 16 + lane] = s; redQ[w * 64 + nf * 16 + lane] = q; }
    }
    __syncthreads();
    if (t < 64) {
        float s = redS[t] + redS[64 + t] + redS[128 + t] + redS[192 + t];
        float q = redQ[t] + redQ[64 + t] + redQ[128 + t] + redQ[192 + t];
        float* st = stats1 + (blockIdx.x & 7) * 128;
        atomicAdd(&st[t], s);
        atomicAdd(&st[64 + t], q);
    }
}

// ---------------- stats2 ----------------
__global__ __launch_bounds__(256, 2) void k_s2(const int* __restrict__ gidx,
                                               const float* __restrict__ src_xyz,
                                               const float* __restrict__ xyz,
                                               const float* __restrict__ src_x,
                                               const short* __restrict__ w1b,
                                               const short* __restrict__ w2b,
                                               const float* __restrict__ g1,
                                               const float* __restrict__ b1,
                                               const float* __restrict__ stats1,
                                               float* __restrict__ stats2) {
    __shared__ short featS[128 * 72];
    __shared__ short h1S[128 * 72];
    __shared__ int sidx[128];
    __shared__ float sc1L[64], sh1L[64];
    __shared__ float redS[512], redQ[512];
    int t = threadIdx.x, lane = t & 63, w = t >> 6;
    if (t < 64) {
        float s = 0.f, q = 0.f;
#pragma unroll
        for (int r = 0; r < 8; ++r) { s += stats1[r * 128 + t]; q += stats1[r * 128 + 64 + t]; }
        float mu = s * (1.f / S1f);
        float var = q * (1.f / S1f) - mu * mu;
        float rs = rsqrtf(var + EPSV);
        float sc = g1[t] * rs;
        sc1L[t] = sc;
        sh1L[t] = b1[t] - mu * sc;
    }
    gather_feat(blockIdx.x * 4, gidx, src_xyz, xyz, src_x, featS, sidx);
    f32x4 acc[2][4];
    layer1_mfma(featS, w1b, lane, w, acc);
#pragma unroll
    for (int rf = 0; rf < 2; ++rf)
#pragma unroll
        for (int nf = 0; nf < 4; ++nf) {
            int col = nf * 16 + (lane & 15);
            float sc = sc1L[col], sh = sh1L[col];
            int row0 = w * 32 + rf * 16 + (lane >> 4) * 4;
#pragma unroll
            for (int j = 0; j < 4; ++j)
                h1S[(row0 + j) * 72 + col] = f2b(gelu_t(acc[rf][nf][j] * sc + sh));
        }
    short8 bw2[2][8];
#pragma unroll
    for (int kf = 0; kf < 2; ++kf)
#pragma unroll
        for (int nf = 0; nf < 8; ++nf)
            bw2[kf][nf] = *(const short8*)(w2b + (nf * 16 + (lane & 15)) * 64 + kf * 32 + (lane >> 4) * 8);
    f32x4 acc2[2][8];
#pragma unroll
    for (int rf = 0; rf < 2; ++rf)
#pragma unroll
        for (int nf = 0; nf < 8; ++nf) acc2[rf][nf] = zero4();
#pragma unroll
    for (int rf = 0; rf < 2; ++rf)
#pragma unroll
        for (int kf = 0; kf < 2; ++kf) {
            short8 a = *(const short8*)(h1S + (w * 32 + rf * 16 + (lane & 15)) * 72 + kf * 32 + (lane >> 4) * 8);
#pragma unroll
            for (int nf = 0; nf < 8; ++nf) acc2[rf][nf] = mfma(a, bw2[kf][nf], acc2[rf][nf]);
        }
#pragma unroll
    for (int nf = 0; nf < 8; ++nf) {
        float s = 0.f, q = 0.f;
#pragma unroll
        for (int rf = 0; rf < 2; ++rf)
#pragma unroll
            for (int j = 0; j < 4; ++j) { float v = acc2[rf][nf][j]; s += v; q += v * v; }
        s += __shfl_xor(s, 16); s += __shfl_xor(s, 32);
        q += __shfl_xor(q, 16); q += __shfl_xor(q, 32);
        if (lane < 16) { redS[w * 128 + nf * 16 + lane] = s; redQ[w * 128 + nf * 16 + lane] = q; }
    }
    __syncthreads();
    if (t < 128) {
        float s = redS[t] + redS[128 + t] + redS[256 + t] + redS[384 + t];
        float q = redQ[t] + redQ[128 + t] + redQ[256 + t] + redQ[384 + t];
        float* st = stats2 + (blockIdx.x & 7) * 256;
        atomicAdd(&st[t], s);
        atomicAdd(&st[128 + t], q);
    }
}

// ---------------- layer3 ----------------
__global__ __launch_bounds__(256, 2) void k_l3(const int* __restrict__ gidx,
                                               const float* __restrict__ src_xyz,
                                               const float* __restrict__ xyz,
                                               const float* __restrict__ src_x,
                                               const short* __restrict__ w1b,
                                               const short* __restrict__ w2b,
                                               const short* __restrict__ w3b,
                                               const float* __restrict__ g1,
                                               const float* __restrict__ b1,
                                               const float* __restrict__ g2,
                                               const float* __restrict__ b2,
                                               const float* __restrict__ stats1,
                                               const float* __restrict__ stats2,
                                               float* __restrict__ out) {
    __shared__ short ubuf[128 * 136];  // featS (stride 72) -> h2S (stride 136)
    __shared__ short h1S[128 * 72];
    __shared__ short w3S[64 * 136];
    __shared__ int sidx[128];
    __shared__ float sc1L[64], sh1L[64], sc2L[128], sh2L[128];
    int t = threadIdx.x, lane = t & 63, w = t >> 6;
    if (t < 64) {
        float s = 0.f, q = 0.f;
#pragma unroll
        for (int r = 0; r < 8; ++r) { s += stats1[r * 128 + t]; q += stats1[r * 128 + 64 + t]; }
        float mu = s * (1.f / S1f);
        float var = q * (1.f / S1f) - mu * mu;
        float rs = rsqrtf(var + EPSV);
        float sc = g1[t] * rs;
        sc1L[t] = sc;
        sh1L[t] = b1[t] - mu * sc;
    }
    if (t < 128) {
        float s = 0.f, q = 0.f;
#pragma unroll
        for (int r = 0; r < 8; ++r) { s += stats2[r * 256 + t]; q += stats2[r * 256 + 128 + t]; }
        float mu = s * (1.f / S1f);
        float var = q * (1.f / S1f) - mu * mu;
        float rs = rsqrtf(var + EPSV);
        float sc = g2[t] * rs;
        sc2L[t] = sc;
        sh2L[t] = b2[t] - mu * sc;
    }
    gather_feat(blockIdx.x * 4, gidx, src_xyz, xyz, src_x, ubuf, sidx);
    f32x4 acc[2][4];
    layer1_mfma(ubuf, w1b, lane, w, acc);
#pragma unroll
    for (int rf = 0; rf < 2; ++rf)
#pragma unroll
        for (int nf = 0; nf < 4; ++nf) {
            int col = nf * 16 + (lane & 15);
            float sc = sc1L[col], sh = sh1L[col];
            int row0 = w * 32 + rf * 16 + (lane >> 4) * 4;
#pragma unroll
            for (int j = 0; j < 4; ++j)
                h1S[(row0 + j) * 72 + col] = f2b(gelu_t(acc[rf][nf][j] * sc + sh));
        }
    __syncthreads();  // featS reads complete before ubuf reused as h2S
    short8 bw2[2][8];
#pragma unroll
    for (int kf = 0; kf < 2; ++kf)
#pragma unroll
        for (int nf = 0; nf < 8; ++nf)
            bw2[kf][nf] = *(const short8*)(w2b + (nf * 16 + (lane & 15)) * 64 + kf * 32 + (lane >> 4) * 8);
    f32x4 acc2[2][8];
#pragma unroll
    for (int rf = 0; rf < 2; ++rf)
#pragma unroll
        for (int nf = 0; nf < 8; ++nf) acc2[rf][nf] = zero4();
#pragma unroll
    for (int rf = 0; rf < 2; ++rf)
#pragma unroll
        for (int kf = 0; kf < 2; ++kf) {
            short8 a = *(const short8*)(h1S + (w * 32 + rf * 16 + (lane & 15)) * 72 + kf * 32 + (lane >> 4) * 8);
#pragma unroll
            for (int nf = 0; nf < 8; ++nf) acc2[rf][nf] = mfma(a, bw2[kf][nf], acc2[rf][nf]);
        }
#pragma unroll
    for (int rf = 0; rf < 2; ++rf)
#pragma unroll
        for (int nf = 0; nf < 8; ++nf) {
            int col = nf * 16 + (lane & 15);
            float sc = sc2L[col], sh = sh2L[col];
            int row0 = w * 32 + rf * 16 + (lane >> 4) * 4;
#pragma unroll
            for (int j = 0; j < 4; ++j)
                ubuf[(row0 + j) * 136 + col] = f2b(gelu_t(acc2[rf][nf][j] * sc + sh));
        }
    int g = blockIdx.x * 4 + w;
    for (int nc = 0; nc < 4; ++nc) {
        __syncthreads();
        {
            const short8* sp = (const short8*)(w3b + (size_t)(nc * 64 + (t >> 2)) * 128 + (t & 3) * 32);
            short8* dp = (short8*)(w3S + (t >> 2) * 136 + (t & 3) * 32);
#pragma unroll
            for (int i = 0; i < 4; ++i) dp[i] = sp[i];
        }
        __syncthreads();
        short8 bw3[4][4];
#pragma unroll
        for (int kf = 0; kf < 4; ++kf)
#pragma unroll
            for (int nf = 0; nf < 4; ++nf)
                bw3[kf][nf] = *(const short8*)(w3S + (nf * 16 + (lane & 15)) * 136 + kf * 32 + (lane >> 4) * 8);
        f32x4 acc3[2][4];
#pragma unroll
        for (int rf = 0; rf < 2; ++rf)
#pragma unroll
            for (int nf = 0; nf < 4; ++nf) acc3[rf][nf] = zero4();
#pragma unroll
        for (int rf = 0; rf < 2; ++rf)
#pragma unroll
            for (int kf = 0; kf < 4; ++kf) {
                short8 a = *(const short8*)(ubuf + (w * 32 + rf * 16 + (lane & 15)) * 136 + kf * 32 + (lane >> 4) * 8);
#pragma unroll
                for (int nf = 0; nf < 4; ++nf) acc3[rf][nf] = mfma(a, bw3[kf][nf], acc3[rf][nf]);
            }
#pragma unroll
        for (int nf = 0; nf < 4; ++nf) {
            float m = fmaxf(fmaxf(fmaxf(acc3[0][nf][0], acc3[0][nf][1]), fmaxf(acc3[0][nf][2], acc3[0][nf][3])),
                            fmaxf(fmaxf(acc3[1][nf][0], acc3[1][nf][1]), fmaxf(acc3[1][nf][2], acc3[1][nf][3])));
            m = fmaxf(m, __shfl_xor(m, 16));
            m = fmaxf(m, __shfl_xor(m, 32));
            if (lane < 16) out[(size_t)g * 256 + nc * 64 + nf * 16 + lane] = m;
        }
    }
}

// ---------------- stats3 + final BN/GELU ----------------
__global__ __launch_bounds__(256) void k_stats3(const float* __restrict__ out,
                                                float* __restrict__ stats3) {
    int t = threadIdx.x;
    float s = 0.f, q = 0.f;
    const float* p = out + (size_t)blockIdx.x * 128 * 256 + t;
    for (int r = 0; r < 128; ++r) { float v = p[r * 256]; s += v; q += v * v; }
    atomicAdd(&stats3[t], s);
    atomicAdd(&stats3[256 + t], q);
}

__global__ __launch_bounds__(256) void k_bn3(float* __restrict__ out,
                                             const float* __restrict__ stats3,
                                             const float* __restrict__ gl,
                                             const float* __restrict__ bl) {
    int i = blockIdx.x * 256 + threadIdx.x;
    int o = i & 255;
    float mu = stats3[o] * (1.f / S3f);
    float var = stats3[256 + o] * (1.f / S3f) - mu * mu;
    float rs = rsqrtf(var + EPSV);
    float x = out[i];
    out[i] = gelu_e((x - mu) * rs * gl[o] + bl[o]);
}

extern "C" void kernel_launch(void* const* d_in, const int* in_sizes, int n_in,
                              void* d_out, int out_size, void* d_ws, size_t ws_size,
                              hipStream_t stream) {
    const float* src_x   = (const float*)d_in[0];
    const float* src_xyz = (const float*)d_in[1];
    const float* xyz     = (const float*)d_in[2];
    const float* w1      = (const float*)d_in[3];
    const float* g1      = (const float*)d_in[4];
    const float* b1      = (const float*)d_in[5];
    const float* w2      = (const float*)d_in[6];
    const float* g2      = (const float*)d_in[7];
    const float* b2      = (const float*)d_in[8];
    const float* w3      = (const float*)d_in[9];
    const float* gl      = (const float*)d_in[10];
    const float* bl      = (const float*)d_in[11];
    float* out = (float*)d_out;

    int* gidx = (int*)d_ws;
    float* statsF = (float*)(gidx + BB * MM * KNN);
    float* stats1 = statsF;          // 8 slots x (64 sum | 64 sq)
    float* stats2 = statsF + 1024;   // 8 slots x (128 sum | 128 sq)
    float* stats3 = statsF + 3072;   // 256 sum + 256 sq
    short* wb = (short*)(statsF + 3584);
    short* w1b = wb;                 // [64][96]
    short* w2b = wb + 6144;          // [128][64]
    short* w3b = wb + 14336;         // [256][128]

    hipMemsetAsync(statsF, 0, 3584 * sizeof(float), stream);
    k_prep<<<184, 256, 0, stream>>>(w1, w2, w3, w1b, w2b, w3b);
    k_ballquery<<<BB * 16, 64, 0, stream>>>(src_xyz, xyz, gidx);
    k_s1<<<(BB * MM) / 4, 256, 0, stream>>>(gidx, src_xyz, xyz, src_x, w1b, stats1);
    k_s2<<<(BB * MM) / 4, 256, 0, stream>>>(gidx, src_xyz, xyz, src_x, w1b, w2b, g1, b1,
                                            stats1, stats2);
    k_l3<<<(BB * MM) / 4, 256, 0, stream>>>(gidx, src_xyz, xyz, src_x, w1b, w2b, w3b,
                                            g1, b1, g2, b2, stats1, stats2, out);
    k_stats3<<<(BB * MM) / 128, 256, 0, stream>>>(out, stats3);
    k_bn3<<<BB * MM, 256, 0, stream>>>(out, stats3, gl, bl);
}

// Round 3
// 342.218 us; speedup vs baseline: 10.6506x; 2.2944x over previous
//
#include <hip/hip_runtime.h>
#include <math.h>

#define BB 16
#define NN 4096
#define MM 1024
#define KNN 32
#define R2 0.04f
#define EPSV 1e-5f
#define S1f ((float)(BB * MM * KNN))
#define S3f ((float)(BB * MM))

typedef __attribute__((ext_vector_type(8))) short short8;
typedef __attribute__((ext_vector_type(4))) float f32x4;

__device__ __forceinline__ short f2b(float x) {
    union { float f; unsigned u; } v; v.f = x;
    unsigned r = v.u + 0x7fffu + ((v.u >> 16) & 1u);
    return (short)(r >> 16);
}
__device__ __forceinline__ float gelu_t(float x) {  // tanh-approx (inner layers, BN-washed)
    float u = 0.7978845608f * x * (1.f + 0.044715f * x * x);
    float t = 1.f - 2.f / (__expf(2.f * u) + 1.f);
    return 0.5f * x * (1.f + t);
}
__device__ __forceinline__ float gelu_e(float x) {  // exact (final output)
    return 0.5f * x * (1.f + erff(x * 0.7071067811865475f));
}
__device__ __forceinline__ f32x4 zero4() { f32x4 z = {0.f, 0.f, 0.f, 0.f}; return z; }
__device__ __forceinline__ f32x4 mfma(short8 a, short8 b, f32x4 c) {
    return __builtin_amdgcn_mfma_f32_16x16x32_bf16(a, b, c, 0, 0, 0);
}

// ---------------- ball query: one query per WAVE ----------------
// 64 lanes test 64 candidates/iter; ballot+popcount gives in-order ranks;
// early-exit at 32 hits. Identical semantics to serial first-K scan.
// Block = 256 threads (4 waves) x 4 queries/wave = 16 queries/block.
__global__ __launch_bounds__(256) void k_ballquery(const float* __restrict__ src_xyz,
                                                   const float* __restrict__ xyz,
                                                   int* __restrict__ gidx) {
    __shared__ float sx[NN], sy[NN], sz[NN];
    int t = threadIdx.x;
    int lane = t & 63, w = t >> 6;
    int q0 = blockIdx.x * 16;          // 16 queries per block, batch-aligned
    int b = q0 >> 10;
    const float* sp = src_xyz + (size_t)b * NN * 3;
    for (int i = t; i < NN * 3; i += 256) {
        float v = sp[i];
        int j = i / 3, d = i - j * 3;
        if (d == 0) sx[j] = v;
        else if (d == 1) sy[j] = v;
        else sz[j] = v;
    }
    __syncthreads();
#pragma unroll
    for (int qi = 0; qi < 4; ++qi) {
        int q = q0 + w * 4 + qi;
        int m = q & 1023;
        float qx = xyz[((size_t)b * MM + m) * 3 + 0];
        float qy = xyz[((size_t)b * MM + m) * 3 + 1];
        float qz = xyz[((size_t)b * MM + m) * 3 + 2];
        int* outp = gidx + (size_t)q * KNN;
        int cnt = 0, firstj = -1;
        for (int j0 = 0; j0 < NN && cnt < KNN; j0 += 64) {
            int j = j0 + lane;
            float dx = qx - sx[j];
            float dy = qy - sy[j];
            float dz = qz - sz[j];
            bool hit = (dx * dx + dy * dy + dz * dz) <= R2;
            unsigned long long mask = __ballot(hit);
            if (hit) {
                int rank = cnt + __popcll(mask & ((1ull << lane) - 1ull));
                if (rank < KNN) outp[rank] = j;
            }
            if (firstj < 0 && mask != 0ull) firstj = j0 + __ffsll((long long)mask) - 1;
            cnt += __popcll(mask);
        }
        if (cnt < KNN) {
            int fj = (firstj < 0) ? 0 : firstj;
            for (int k = cnt + lane; k < KNN; k += 64) outp[k] = fj;
        }
    }
}

// ---------------- weights -> bf16 (w1 zero-padded K 67->96) ----------------
__global__ __launch_bounds__(256) void k_prep(const float* __restrict__ w1,
                                              const float* __restrict__ w2,
                                              const float* __restrict__ w3,
                                              short* __restrict__ w1b,
                                              short* __restrict__ w2b,
                                              short* __restrict__ w3b) {
    int i = blockIdx.x * 256 + threadIdx.x;
    if (i < 64 * 96) {
        int n = i / 96, k = i % 96;
        w1b[i] = (k < 67) ? f2b(w1[n * 67 + k]) : (short)0;
    } else if (i < 64 * 96 + 128 * 64) {
        int j = i - 64 * 96;
        w2b[j] = f2b(w2[j]);
    } else if (i < 64 * 96 + 128 * 64 + 256 * 128) {
        int j = i - (64 * 96 + 128 * 64);
        w3b[j] = f2b(w3[j]);
    }
}

// ---------------- gather 128 rows (4 groups) into featS[128][72] bf16 ----------------
__device__ __forceinline__ void gather_feat(int g0, const int* __restrict__ gidx,
                                            const float* __restrict__ src_xyz,
                                            const float* __restrict__ xyz,
                                            const float* __restrict__ src_x,
                                            short* featS, int* sidx) {
    int t = threadIdx.x;
    if (t < 128) sidx[t] = gidx[(size_t)(g0 + (t >> 5)) * KNN + (t & 31)];
    __syncthreads();
    if (t < 128) {
        int gg = g0 + (t >> 5);
        int b = gg >> 10, m = gg & 1023;
        int j = sidx[t];
        const float* sp = src_xyz + ((size_t)b * NN + j) * 3;
        const float* qp = xyz + ((size_t)b * MM + m) * 3;
        short* d = featS + t * 72;
        d[0] = f2b(sp[0] - qp[0]);
        d[1] = f2b(sp[1] - qp[1]);
        d[2] = f2b(sp[2] - qp[2]);
        d[67] = 0; d[68] = 0; d[69] = 0; d[70] = 0; d[71] = 0;
    }
    {
        int r = t >> 1, hf = t & 1;
        int gg = g0 + (r >> 5);
        int b = gg >> 10;
        const f32x4* xp = (const f32x4*)(src_x + ((size_t)b * NN + sidx[r]) * 64 + hf * 32);
        short* d = featS + r * 72 + 3 + hf * 32;
#pragma unroll
        for (int i = 0; i < 8; ++i) {
            f32x4 v = xp[i];
            d[i * 4 + 0] = f2b(v[0]); d[i * 4 + 1] = f2b(v[1]);
            d[i * 4 + 2] = f2b(v[2]); d[i * 4 + 3] = f2b(v[3]);
        }
    }
    __syncthreads();
}

__device__ __forceinline__ void layer1_mfma(const short* featS, const short* __restrict__ w1b,
                                            int lane, int w, f32x4 acc[2][4]) {
#pragma unroll
    for (int rf = 0; rf < 2; ++rf)
#pragma unroll
        for (int nf = 0; nf < 4; ++nf) acc[rf][nf] = zero4();
    short8 bw[3][4];
#pragma unroll
    for (int kf = 0; kf < 3; ++kf)
#pragma unroll
        for (int nf = 0; nf < 4; ++nf)
            bw[kf][nf] = *(const short8*)(w1b + (nf * 16 + (lane & 15)) * 96 + kf * 32 + (lane >> 4) * 8);
#pragma unroll
    for (int rf = 0; rf < 2; ++rf) {
#pragma unroll
        for (int kf = 0; kf < 3; ++kf) {
            short8 a = {0, 0, 0, 0, 0, 0, 0, 0};
            if (kf < 2 || (lane >> 4) == 0)
                a = *(const short8*)(featS + (w * 32 + rf * 16 + (lane & 15)) * 72 + kf * 32 + (lane >> 4) * 8);
#pragma unroll
            for (int nf = 0; nf < 4; ++nf) acc[rf][nf] = mfma(a, bw[kf][nf], acc[rf][nf]);
        }
    }
}

// ---------------- stats1 ----------------
__global__ __launch_bounds__(256, 2) void k_s1(const int* __restrict__ gidx,
                                               const float* __restrict__ src_xyz,
                                               const float* __restrict__ xyz,
                                               const float* __restrict__ src_x,
                                               const short* __restrict__ w1b,
                                               float* __restrict__ stats1) {
    __shared__ short featS[128 * 72];
    __shared__ int sidx[128];
    __shared__ float redS[256], redQ[256];
    int t = threadIdx.x, lane = t & 63, w = t >> 6;
    gather_feat(blockIdx.x * 4, gidx, src_xyz, xyz, src_x, featS, sidx);
    f32x4 acc[2][4];
    layer1_mfma(featS, w1b, lane, w, acc);
#pragma unroll
    for (int nf = 0; nf < 4; ++nf) {
        float s = 0.f, q = 0.f;
#pragma unroll
        for (int rf = 0; rf < 2; ++rf)
#pragma unroll
            for (int j = 0; j < 4; ++j) { float v = acc[rf][nf][j]; s += v; q += v * v; }
        s += __shfl_xor(s, 16); s += __shfl_xor(s, 32);
        q += __shfl_xor(q, 16); q += __shfl_xor(q, 32);
        if (lane < 16) { redS[w * 64 + nf * 16 + lane] = s; redQ[w * 64 + nf * 16 + lane] = q; }
    }
    __syncthreads();
    if (t < 64) {
        float s = redS[t] + redS[64 + t] + redS[128 + t] + redS[192 + t];
        float q = redQ[t] + redQ[64 + t] + redQ[128 + t] + redQ[192 + t];
        float* st = stats1 + (blockIdx.x & 7) * 128;
        atomicAdd(&st[t], s);
        atomicAdd(&st[64 + t], q);
    }
}

// ---------------- stats2 ----------------
__global__ __launch_bounds__(256, 2) void k_s2(const int* __restrict__ gidx,
                                               const float* __restrict__ src_xyz,
                                               const float* __restrict__ xyz,
                                               const float* __restrict__ src_x,
                                               const short* __restrict__ w1b,
                                               const short* __restrict__ w2b,
                                               const float* __restrict__ g1,
                                               const float* __restrict__ b1,
                                               const float* __restrict__ stats1,
                                               float* __restrict__ stats2) {
    __shared__ short featS[128 * 72];
    __shared__ short h1S[128 * 72];
    __shared__ int sidx[128];
    __shared__ float sc1L[64], sh1L[64];
    __shared__ float redS[512], redQ[512];
    int t = threadIdx.x, lane = t & 63, w = t >> 6;
    if (t < 64) {
        float s = 0.f, q = 0.f;
#pragma unroll
        for (int r = 0; r < 8; ++r) { s += stats1[r * 128 + t]; q += stats1[r * 128 + 64 + t]; }
        float mu = s * (1.f / S1f);
        float var = q * (1.f / S1f) - mu * mu;
        float rs = rsqrtf(var + EPSV);
        float sc = g1[t] * rs;
        sc1L[t] = sc;
        sh1L[t] = b1[t] - mu * sc;
    }
    gather_feat(blockIdx.x * 4, gidx, src_xyz, xyz, src_x, featS, sidx);
    f32x4 acc[2][4];
    layer1_mfma(featS, w1b, lane, w, acc);
#pragma unroll
    for (int rf = 0; rf < 2; ++rf)
#pragma unroll
        for (int nf = 0; nf < 4; ++nf) {
            int col = nf * 16 + (lane & 15);
            float sc = sc1L[col], sh = sh1L[col];
            int row0 = w * 32 + rf * 16 + (lane >> 4) * 4;
#pragma unroll
            for (int j = 0; j < 4; ++j)
                h1S[(row0 + j) * 72 + col] = f2b(gelu_t(acc[rf][nf][j] * sc + sh));
        }
    short8 bw2[2][8];
#pragma unroll
    for (int kf = 0; kf < 2; ++kf)
#pragma unroll
        for (int nf = 0; nf < 8; ++nf)
            bw2[kf][nf] = *(const short8*)(w2b + (nf * 16 + (lane & 15)) * 64 + kf * 32 + (lane >> 4) * 8);
    f32x4 acc2[2][8];
#pragma unroll
    for (int rf = 0; rf < 2; ++rf)
#pragma unroll
        for (int nf = 0; nf < 8; ++nf) acc2[rf][nf] = zero4();
#pragma unroll
    for (int rf = 0; rf < 2; ++rf)
#pragma unroll
        for (int kf = 0; kf < 2; ++kf) {
            short8 a = *(const short8*)(h1S + (w * 32 + rf * 16 + (lane & 15)) * 72 + kf * 32 + (lane >> 4) * 8);
#pragma unroll
            for (int nf = 0; nf < 8; ++nf) acc2[rf][nf] = mfma(a, bw2[kf][nf], acc2[rf][nf]);
        }
#pragma unroll
    for (int nf = 0; nf < 8; ++nf) {
        float s = 0.f, q = 0.f;
#pragma unroll
        for (int rf = 0; rf < 2; ++rf)
#pragma unroll
            for (int j = 0; j < 4; ++j) { float v = acc2[rf][nf][j]; s += v; q += v * v; }
        s += __shfl_xor(s, 16); s += __shfl_xor(s, 32);
        q += __shfl_xor(q, 16); q += __shfl_xor(q, 32);
        if (lane < 16) { redS[w * 128 + nf * 16 + lane] = s; redQ[w * 128 + nf * 16 + lane] = q; }
    }
    __syncthreads();
    if (t < 128) {
        float s = redS[t] + redS[128 + t] + redS[256 + t] + redS[384 + t];
        float q = redQ[t] + redQ[128 + t] + redQ[256 + t] + redQ[384 + t];
        float* st = stats2 + (blockIdx.x & 7) * 256;
        atomicAdd(&st[t], s);
        atomicAdd(&st[128 + t], q);
    }
}

// ---------------- layer3 ----------------
__global__ __launch_bounds__(256, 2) void k_l3(const int* __restrict__ gidx,
                                               const float* __restrict__ src_xyz,
                                               const float* __restrict__ xyz,
                                               const float* __restrict__ src_x,
                                               const short* __restrict__ w1b,
                                               const short* __restrict__ w2b,
                                               const short* __restrict__ w3b,
                                               const float* __restrict__ g1,
                                               const float* __restrict__ b1,
                                               const float* __restrict__ g2,
                                               const float* __restrict__ b2,
                                               const float* __restrict__ stats1,
                                               const float* __restrict__ stats2,
                                               float* __restrict__ out) {
    __shared__ short ubuf[128 * 136];  // featS (stride 72) -> h2S (stride 136)
    __shared__ short h1S[128 * 72];
    __shared__ short w3S[64 * 136];
    __shared__ int sidx[128];
    __shared__ float sc1L[64], sh1L[64], sc2L[128], sh2L[128];
    int t = threadIdx.x, lane = t & 63, w = t >> 6;
    if (t < 64) {
        float s = 0.f, q = 0.f;
#pragma unroll
        for (int r = 0; r < 8; ++r) { s += stats1[r * 128 + t]; q += stats1[r * 128 + 64 + t]; }
        float mu = s * (1.f / S1f);
        float var = q * (1.f / S1f) - mu * mu;
        float rs = rsqrtf(var + EPSV);
        float sc = g1[t] * rs;
        sc1L[t] = sc;
        sh1L[t] = b1[t] - mu * sc;
    }
    if (t < 128) {
        float s = 0.f, q = 0.f;
#pragma unroll
        for (int r = 0; r < 8; ++r) { s += stats2[r * 256 + t]; q += stats2[r * 256 + 128 + t]; }
        float mu = s * (1.f / S1f);
        float var = q * (1.f / S1f) - mu * mu;
        float rs = rsqrtf(var + EPSV);
        float sc = g2[t] * rs;
        sc2L[t] = sc;
        sh2L[t] = b2[t] - mu * sc;
    }
    gather_feat(blockIdx.x * 4, gidx, src_xyz, xyz, src_x, ubuf, sidx);
    f32x4 acc[2][4];
    layer1_mfma(ubuf, w1b, lane, w, acc);
#pragma unroll
    for (int rf = 0; rf < 2; ++rf)
#pragma unroll
        for (int nf = 0; nf < 4; ++nf) {
            int col = nf * 16 + (lane & 15);
            float sc = sc1L[col], sh = sh1L[col];
            int row0 = w * 32 + rf * 16 + (lane >> 4) * 4;
#pragma unroll
            for (int j = 0; j < 4; ++j)
                h1S[(row0 + j) * 72 + col] = f2b(gelu_t(acc[rf][nf][j] * sc + sh));
        }
    __syncthreads();  // featS reads complete before ubuf reused as h2S
    short8 bw2[2][8];
#pragma unroll
    for (int kf = 0; kf < 2; ++kf)
#pragma unroll
        for (int nf = 0; nf < 8; ++nf)
            bw2[kf][nf] = *(const short8*)(w2b + (nf * 16 + (lane & 15)) * 64 + kf * 32 + (lane >> 4) * 8);
    f32x4 acc2[2][8];
#pragma unroll
    for (int rf = 0; rf < 2; ++rf)
#pragma unroll
        for (int nf = 0; nf < 8; ++nf) acc2[rf][nf] = zero4();
#pragma unroll
    for (int rf = 0; rf < 2; ++rf)
#pragma unroll
        for (int kf = 0; kf < 2; ++kf) {
            short8 a = *(const short8*)(h1S + (w * 32 + rf * 16 + (lane & 15)) * 72 + kf * 32 + (lane >> 4) * 8);
#pragma unroll
            for (int nf = 0; nf < 8; ++nf) acc2[rf][nf] = mfma(a, bw2[kf][nf], acc2[rf][nf]);
        }
#pragma unroll
    for (int rf = 0; rf < 2; ++rf)
#pragma unroll
        for (int nf = 0; nf < 8; ++nf) {
            int col = nf * 16 + (lane & 15);
            float sc = sc2L[col], sh = sh2L[col];
            int row0 = w * 32 + rf * 16 + (lane >> 4) * 4;
#pragma unroll
            for (int j = 0; j < 4; ++j)
                ubuf[(row0 + j) * 136 + col] = f2b(gelu_t(acc2[rf][nf][j] * sc + sh));
        }
    int g = blockIdx.x * 4 + w;
    for (int nc = 0; nc < 4; ++nc) {
        __syncthreads();
        {
            const short8* sp = (const short8*)(w3b + (size_t)(nc * 64 + (t >> 2)) * 128 + (t & 3) * 32);
            short8* dp = (short8*)(w3S + (t >> 2) * 136 + (t & 3) * 32);
#pragma unroll
            for (int i = 0; i < 4; ++i) dp[i] = sp[i];
        }
        __syncthreads();
        short8 bw3[4][4];
#pragma unroll
        for (int kf = 0; kf < 4; ++kf)
#pragma unroll
            for (int nf = 0; nf < 4; ++nf)
                bw3[kf][nf] = *(const short8*)(w3S + (nf * 16 + (lane & 15)) * 136 + kf * 32 + (lane >> 4) * 8);
        f32x4 acc3[2][4];
#pragma unroll
        for (int rf = 0; rf < 2; ++rf)
#pragma unroll
            for (int nf = 0; nf < 4; ++nf) acc3[rf][nf] = zero4();
#pragma unroll
        for (int rf = 0; rf < 2; ++rf)
#pragma unroll
            for (int kf = 0; kf < 4; ++kf) {
                short8 a = *(const short8*)(ubuf + (w * 32 + rf * 16 + (lane & 15)) * 136 + kf * 32 + (lane >> 4) * 8);
#pragma unroll
                for (int nf = 0; nf < 4; ++nf) acc3[rf][nf] = mfma(a, bw3[kf][nf], acc3[rf][nf]);
            }
#pragma unroll
        for (int nf = 0; nf < 4; ++nf) {
            float m = fmaxf(fmaxf(fmaxf(acc3[0][nf][0], acc3[0][nf][1]), fmaxf(acc3[0][nf][2], acc3[0][nf][3])),
                            fmaxf(fmaxf(acc3[1][nf][0], acc3[1][nf][1]), fmaxf(acc3[1][nf][2], acc3[1][nf][3])));
            m = fmaxf(m, __shfl_xor(m, 16));
            m = fmaxf(m, __shfl_xor(m, 32));
            if (lane < 16) out[(size_t)g * 256 + nc * 64 + nf * 16 + lane] = m;
        }
    }
}

// ---------------- stats3 + final BN/GELU ----------------
__global__ __launch_bounds__(256) void k_stats3(const float* __restrict__ out,
                                                float* __restrict__ stats3) {
    int t = threadIdx.x;
    float s = 0.f, q = 0.f;
    const float* p = out + (size_t)blockIdx.x * 128 * 256 + t;
    for (int r = 0; r < 128; ++r) { float v = p[r * 256]; s += v; q += v * v; }
    atomicAdd(&stats3[t], s);
    atomicAdd(&stats3[256 + t], q);
}

__global__ __launch_bounds__(256) void k_bn3(float* __restrict__ out,
                                             const float* __restrict__ stats3,
                                             const float* __restrict__ gl,
                                             const float* __restrict__ bl) {
    int i = blockIdx.x * 256 + threadIdx.x;
    int o = i & 255;
    float mu = stats3[o] * (1.f / S3f);
    float var = stats3[256 + o] * (1.f / S3f) - mu * mu;
    float rs = rsqrtf(var + EPSV);
    float x = out[i];
    out[i] = gelu_e((x - mu) * rs * gl[o] + bl[o]);
}

extern "C" void kernel_launch(void* const* d_in, const int* in_sizes, int n_in,
                              void* d_out, int out_size, void* d_ws, size_t ws_size,
                              hipStream_t stream) {
    const float* src_x   = (const float*)d_in[0];
    const float* src_xyz = (const float*)d_in[1];
    const float* xyz     = (const float*)d_in[2];
    const float* w1      = (const float*)d_in[3];
    const float* g1      = (const float*)d_in[4];
    const float* b1      = (const float*)d_in[5];
    const float* w2      = (const float*)d_in[6];
    const float* g2      = (const float*)d_in[7];
    const float* b2      = (const float*)d_in[8];
    const float* w3      = (const float*)d_in[9];
    const float* gl      = (const float*)d_in[10];
    const float* bl      = (const float*)d_in[11];
    float* out = (float*)d_out;

    int* gidx = (int*)d_ws;
    float* statsF = (float*)(gidx + BB * MM * KNN);
    float* stats1 = statsF;          // 8 slots x (64 sum | 64 sq)
    float* stats2 = statsF + 1024;   // 8 slots x (128 sum | 128 sq)
    float* stats3 = statsF + 3072;   // 256 sum + 256 sq
    short* wb = (short*)(statsF + 3584);
    short* w1b = wb;                 // [64][96]
    short* w2b = wb + 6144;          // [128][64]
    short* w3b = wb + 14336;         // [256][128]

    hipMemsetAsync(statsF, 0, 3584 * sizeof(float), stream);
    k_prep<<<184, 256, 0, stream>>>(w1, w2, w3, w1b, w2b, w3b);
    k_ballquery<<<(BB * MM) / 16, 256, 0, stream>>>(src_xyz, xyz, gidx);
    k_s1<<<(BB * MM) / 4, 256, 0, stream>>>(gidx, src_xyz, xyz, src_x, w1b, stats1);
    k_s2<<<(BB * MM) / 4, 256, 0, stream>>>(gidx, src_xyz, xyz, src_x, w1b, w2b, g1, b1,
                                            stats1, stats2);
    k_l3<<<(BB * MM) / 4, 256, 0, stream>>>(gidx, src_xyz, xyz, src_x, w1b, w2b, w3b,
                                            g1, b1, g2, b2, stats1, stats2, out);
    k_stats3<<<(BB * MM) / 128, 256, 0, stream>>>(out, stats3);
    k_bn3<<<BB * MM, 256, 0, stream>>>(out, stats3, gl, bl);
}